// Round 1
// baseline (63.611 us; speedup 1.0000x reference)
//
#include <hip/hip_runtime.h>
#include <hip/hip_bf16.h>

// VNETDetector — constant-folded.
//
// PROOF the reference output is identically zero:
//   step(in_prob, llr):
//     bit      = argmin(in_prob) % 2
//     m        = in_prob + llr
//     out_prob = minimum(m[idx0], m[idx1]),  idx0 = arange(16)//2, idx1 = idx0+8
//   idx0 = [0,0,1,1,2,2,...,7,7]  =>  out_prob[2u] and out_prob[2u+1] are the
//   SAME expression min(m[u], m[u+8]) — bitwise identical. Hence every carry
//   vector v_k (k>=1) has v_k[2u] == v_k[2u+1] bitwise; v_0 = zeros.
//   jnp.argmin tie-breaks to the first occurrence, so argmin(v_k) is always
//   an even index => bit_k = 0 for all k, for ANY inputs (weights, y, even
//   NaNs — pairs stay bitwise equal, so the first min/NaN index is even).
//   Therefore reference(...) == zeros((1, L), float32).
//
// The DNN priors and the 262144-step sequential min-plus scan fold away.
// Optimal kernel: zero-fill d_out (1 MB of fp32). Harness re-poisons d_out
// to 0xAA before every timed launch, so we must write all elements each call.

#define L_TOTAL 262144

__global__ __launch_bounds__(256) void vnet_zero_fill(float4* __restrict__ out) {
    // 256 blocks x 256 threads x 1 float4 = 65536 float4 = 262144 floats = 1 MB
    int idx = blockIdx.x * blockDim.x + threadIdx.x;
    out[idx] = make_float4(0.f, 0.f, 0.f, 0.f);
}

extern "C" void kernel_launch(void* const* d_in, const int* in_sizes, int n_in,
                              void* d_out, int out_size, void* d_ws, size_t ws_size,
                              hipStream_t stream) {
    (void)d_in; (void)in_sizes; (void)n_in; (void)d_ws; (void)ws_size;
    // out_size == 262144 floats == 65536 float4
    const int n_vec4 = out_size / 4;           // 65536
    const int block  = 256;
    const int grid   = (n_vec4 + block - 1) / block;  // 256
    vnet_zero_fill<<<grid, block, 0, stream>>>((float4*)d_out);
}